// Round 6
// baseline (2407.408 us; speedup 1.0000x reference)
//
#include <hip/hip_runtime.h>
#include <hip/hip_bf16.h>
#include <hip/hip_fp16.h>

// RNN: INPUT=128, HIDDEN=256, OUTPUT=128, BATCH=64, SEQ=2048
// ref: xp[b,s,h] = sum_i x[b,s,i]*W_ih[h,i] + b_ih[h] + b_hh[h]
//      h = tanh(xp_t + h @ W_hh^T)   (scan over s)
//      out = h_T @ W_fc^T + b_fc

#define S_LEN 2048
#define B_SZ  64
#define IN_D  128
#define HID   256
#define OUT_D 128
#define HPAD  264   // LDS h row stride (f16 units): 264*2=528B = 33*16B -> <=2-way banks

typedef _Float16 half8_t __attribute__((ext_vector_type(8)));
typedef float    f32x4   __attribute__((ext_vector_type(4)));

#if __has_builtin(__builtin_amdgcn_exp2f)
#define EXP2F(x) __builtin_amdgcn_exp2f(x)
#else
#define EXP2F(x) exp2f(x)
#endif

#if __has_builtin(__builtin_amdgcn_rcpf)
#define RCPF(x) __builtin_amdgcn_rcpf(x)
#else
#define RCPF(x) (1.0f / (x))
#endif

// ---------------- Kernel A: xp = x @ W_ih^T + b_ih + b_hh  (f16 out to ws) ---
// (unchanged from round 5 — ~128us; optimize later if it becomes the bottleneck)
__global__ __launch_bounds__(256) void xproj_kernel(
    const float* __restrict__ x, const float* __restrict__ W_ih,
    const float* __restrict__ b_ih, const float* __restrict__ b_hh,
    _Float16* __restrict__ xp)
{
    const int lane  = threadIdx.x & 63;
    const int wave  = threadIdx.x >> 6;
    const int idx16 = lane & 15;
    const int kq    = lane >> 4;                       // 0..3
    const int r0    = blockIdx.x * 256 + wave * 64;    // wave's 64 m-rows

    half8_t afr[4][4];
    #pragma unroll
    for (int mt = 0; mt < 4; ++mt) {
        #pragma unroll
        for (int sl = 0; sl < 4; ++sl) {
            const float4* ap = (const float4*)(x + (size_t)(r0 + mt * 16 + idx16) * IN_D + sl * 32 + kq * 8);
            float4 a0 = ap[0], a1 = ap[1];
            afr[mt][sl] = half8_t{(_Float16)a0.x, (_Float16)a0.y, (_Float16)a0.z, (_Float16)a0.w,
                                  (_Float16)a1.x, (_Float16)a1.y, (_Float16)a1.z, (_Float16)a1.w};
        }
    }

    for (int nc = 0; nc < 16; ++nc) {
        const int n0 = nc * 16;
        const float bias = b_ih[n0 + idx16] + b_hh[n0 + idx16];

        half8_t bfr[4];
        #pragma unroll
        for (int sl = 0; sl < 4; ++sl) {
            const float4* bp = (const float4*)(W_ih + (size_t)(n0 + idx16) * IN_D + sl * 32 + kq * 8);
            float4 b0 = bp[0], b1 = bp[1];
            bfr[sl] = half8_t{(_Float16)b0.x, (_Float16)b0.y, (_Float16)b0.z, (_Float16)b0.w,
                              (_Float16)b1.x, (_Float16)b1.y, (_Float16)b1.z, (_Float16)b1.w};
        }

        #pragma unroll
        for (int mt = 0; mt < 4; ++mt) {
            f32x4 acc = {0.f, 0.f, 0.f, 0.f};
            #pragma unroll
            for (int sl = 0; sl < 4; ++sl)
                acc = __builtin_amdgcn_mfma_f32_16x16x32_f16(afr[mt][sl], bfr[sl], acc, 0, 0, 0);
            #pragma unroll
            for (int r = 0; r < 4; ++r) {
                const int m = r0 + mt * 16 + kq * 4 + r;
                xp[(size_t)m * HID + n0 + idx16] = (_Float16)(acc[r] + bias);
            }
        }
    }
}

// ---------------- Kernel B: MFMA recurrence + final FC ----------------------
// 4 blocks x 256 threads (4 waves). Block owns batches [16*bid, 16*bid+16).
// Wave owns hidden cols [64*wave, 64*wave+64): per step 32x mfma 16x16x32
// (M=16 batch, N=64, K=256). W_hh B-fragments = 128 regs/lane, loaded once
// (MFMA reads AGPR operands natively -> AGPR placement is free, unlike the
// dot2 designs of rounds 1-5 which needed the values in VALU-readable VGPRs).
// h double-buffered in LDS [2][16][HPAD] f16; ONE barrier/step (reads happen
// before the barrier, writes go to the other buffer -> no race).
// A-frag (lane l): batch=l&15, k=32s+(l>>4)*8+e  -> ds_read_b128 from h row.
// B-frag (lane l): col n=l&15 (within 16-tile), same k pattern (from W_hh row).
// C/D: col=lane&15 (hidden), row=(lane>>4)*4+r (batch).
template <int CUR>
static __device__ __forceinline__ void rnn_step(
    _Float16 (*hl)[16][HPAD],               // [2][16][HPAD] LDS
    const half8_t (&B)[4][8],
    _Float16 (&pc)[16],                     // xp values for this step (r*4+nt)
    const _Float16* const (&xb)[4],
    int t, int c16, int g, int wave)
{
    // A fragments: full h(t) row slice per lane
    half8_t A[8];
    #pragma unroll
    for (int s = 0; s < 8; ++s)
        A[s] = *(const half8_t*)&hl[CUR][c16][32 * s + g * 8];

    f32x4 C0 = {0.f,0.f,0.f,0.f}, C1 = {0.f,0.f,0.f,0.f};
    f32x4 C2 = {0.f,0.f,0.f,0.f}, C3 = {0.f,0.f,0.f,0.f};
    #pragma unroll
    for (int s = 0; s < 8; ++s) {
        C0 = __builtin_amdgcn_mfma_f32_16x16x32_f16(A[s], B[0][s], C0, 0, 0, 0);
        C1 = __builtin_amdgcn_mfma_f32_16x16x32_f16(A[s], B[1][s], C1, 0, 0, 0);
        C2 = __builtin_amdgcn_mfma_f32_16x16x32_f16(A[s], B[2][s], C2, 0, 0, 0);
        C3 = __builtin_amdgcn_mfma_f32_16x16x32_f16(A[s], B[3][s], C3, 0, 0, 0);
    }

    // consume xp, tanh, write h(t+1) to the other buffer
    #pragma unroll
    for (int nt = 0; nt < 4; ++nt) {
        f32x4 Cv = (nt == 0) ? C0 : (nt == 1) ? C1 : (nt == 2) ? C2 : C3;
        #pragma unroll
        for (int r = 0; r < 4; ++r) {
            const float z = Cv[r] + (float)pc[r * 4 + nt];
            // tanh(z) = 1 - 2/(exp2(2*log2e*z)+1); saturates correctly
            const float e = EXP2F(z * 2.8853900817779268f);
            const float th = 1.f - 2.f * RCPF(e + 1.f);
            hl[CUR ^ 1][g * 4 + r][wave * 64 + nt * 16 + c16] = (_Float16)th;
        }
    }

    // prefetch xp for t+2 into the just-freed bank (consumed above)
    if (t + 2 < S_LEN) {
        #pragma unroll
        for (int r = 0; r < 4; ++r)
            #pragma unroll
            for (int nt = 0; nt < 4; ++nt)
                pc[r * 4 + nt] = xb[r][(size_t)(t + 2) * HID + nt * 16];
    }

    __syncthreads();
}

__global__ __launch_bounds__(256)
__attribute__((amdgpu_waves_per_eu(1, 1)))
void rnn_kernel(
    const _Float16* __restrict__ xp, const float* __restrict__ W_hh,
    const float* __restrict__ W_fc, const float* __restrict__ b_fc,
    float* __restrict__ out)
{
    const int tid  = threadIdx.x;
    const int lane = tid & 63;
    const int wave = tid >> 6;          // 0..3: owns n in [64w, 64w+64)
    const int m0   = blockIdx.x * 16;   // batch base
    const int c16  = lane & 15;
    const int g    = lane >> 4;         // 0..3

    __shared__ __align__(16) _Float16 hlds[2][16][HPAD];   // 16.5 KB

    // ---- B fragments: W_hh rows (n = 64w + 16nt + c16), f32 -> f16 ----
    half8_t B[4][8];
    #pragma unroll
    for (int nt = 0; nt < 4; ++nt) {
        const float* wrow = W_hh + (size_t)(wave * 64 + nt * 16 + c16) * HID + g * 8;
        #pragma unroll
        for (int s = 0; s < 8; ++s) {
            const float4* p = (const float4*)(wrow + 32 * s);
            float4 v0 = p[0], v1 = p[1];
            B[nt][s] = half8_t{(_Float16)v0.x, (_Float16)v0.y, (_Float16)v0.z, (_Float16)v0.w,
                               (_Float16)v1.x, (_Float16)v1.y, (_Float16)v1.z, (_Float16)v1.w};
        }
    }

    // ---- h(0) = 0 ----
    for (int i = tid; i < 16 * HPAD; i += 256)
        ((_Float16*)hlds)[i] = (_Float16)0.f;

    // ---- xp prefetch: value (r,nt) -> batch m0+g*4+r, hid 64w+16nt+c16 ----
    const _Float16* xb[4];
    #pragma unroll
    for (int r = 0; r < 4; ++r)
        xb[r] = xp + (size_t)(m0 + g * 4 + r) * S_LEN * HID + wave * 64 + c16;

    _Float16 pA[16], pB[16];
    #pragma unroll
    for (int r = 0; r < 4; ++r) {
        #pragma unroll
        for (int nt = 0; nt < 4; ++nt) {
            pA[r * 4 + nt] = xb[r][nt * 16];                    // t = 0
            pB[r * 4 + nt] = xb[r][(size_t)HID + nt * 16];      // t = 1
        }
    }

    __syncthreads();

    // ---- 2048 steps, unrolled x2 for static buffer indexing ----
    for (int t = 0; t < S_LEN; t += 2) {
        rnn_step<0>(hlds, B, pA, xb, t,     c16, g, wave);
        rnn_step<1>(hlds, B, pB, xb, t + 1, c16, g, wave);
    }

    // ---- final FC via MFMA: M=16 batch, N=128 out (32/wave), K=256 ----
    // h_final is in hlds[0] (S_LEN even)
    half8_t Bf[2][8];
    #pragma unroll
    for (int nt = 0; nt < 2; ++nt) {
        const float* wrow = W_fc + (size_t)(wave * 32 + nt * 16 + c16) * HID + g * 8;
        #pragma unroll
        for (int s = 0; s < 8; ++s) {
            const float4* p = (const float4*)(wrow + 32 * s);
            float4 v0 = p[0], v1 = p[1];
            Bf[nt][s] = half8_t{(_Float16)v0.x, (_Float16)v0.y, (_Float16)v0.z, (_Float16)v0.w,
                                (_Float16)v1.x, (_Float16)v1.y, (_Float16)v1.z, (_Float16)v1.w};
        }
    }
    half8_t A[8];
    #pragma unroll
    for (int s = 0; s < 8; ++s)
        A[s] = *(const half8_t*)&hlds[0][c16][32 * s + g * 8];

    f32x4 D0 = {0.f,0.f,0.f,0.f}, D1 = {0.f,0.f,0.f,0.f};
    #pragma unroll
    for (int s = 0; s < 8; ++s) {
        D0 = __builtin_amdgcn_mfma_f32_16x16x32_f16(A[s], Bf[0][s], D0, 0, 0, 0);
        D1 = __builtin_amdgcn_mfma_f32_16x16x32_f16(A[s], Bf[1][s], D1, 0, 0, 0);
    }
    #pragma unroll
    for (int nt = 0; nt < 2; ++nt) {
        f32x4 Dv = (nt == 0) ? D0 : D1;
        const int o = wave * 32 + nt * 16 + c16;
        #pragma unroll
        for (int r = 0; r < 4; ++r) {
            const int b = m0 + g * 4 + r;
            out[(size_t)b * OUT_D + o] = Dv[r] + b_fc[o];
        }
    }
}

extern "C" void kernel_launch(void* const* d_in, const int* in_sizes, int n_in,
                              void* d_out, int out_size, void* d_ws, size_t ws_size,
                              hipStream_t stream) {
    const float* x    = (const float*)d_in[0];
    const float* W_ih = (const float*)d_in[1];
    const float* W_hh = (const float*)d_in[2];
    const float* b_ih = (const float*)d_in[3];
    const float* b_hh = (const float*)d_in[4];
    const float* W_fc = (const float*)d_in[5];
    const float* b_fc = (const float*)d_in[6];
    float* outp = (float*)d_out;

    _Float16* xp_ws = (_Float16*)d_ws;   // needs 2048*64*256*2 = 64 MiB

    dim3 gA(S_LEN * B_SZ / 256, 1, 1);   // 512 blocks x 256 rows
    xproj_kernel<<<gA, 256, 0, stream>>>(x, W_ih, b_ih, b_hh, xp_ws);

    rnn_kernel<<<4, 256, 0, stream>>>(xp_ws, W_hh, W_fc, b_fc, outp);
}

// Round 7
// 2055.238 us; speedup vs baseline: 1.1714x; 1.1714x over previous
//
#include <hip/hip_runtime.h>
#include <hip/hip_bf16.h>
#include <hip/hip_fp16.h>

// RNN: INPUT=128, HIDDEN=256, OUTPUT=128, BATCH=64, SEQ=2048
// ref: xp[b,s,h] = sum_i x[b,s,i]*W_ih[h,i] + b_ih[h] + b_hh[h]
//      h = tanh(xp_t + h @ W_hh^T)   (scan over s)
//      out = h_T @ W_fc^T + b_fc

#define S_LEN 2048
#define B_SZ  64
#define IN_D  128
#define HID   256
#define OUT_D 128
#define HPAD  264   // h row stride (f16): 528B; b128 reads at LDS BW floor

typedef _Float16 half8_t __attribute__((ext_vector_type(8)));
typedef float    f32x4   __attribute__((ext_vector_type(4)));

#if __has_builtin(__builtin_amdgcn_exp2f)
#define EXP2F(x) __builtin_amdgcn_exp2f(x)
#else
#define EXP2F(x) exp2f(x)
#endif

#if __has_builtin(__builtin_amdgcn_rcpf)
#define RCPF(x) __builtin_amdgcn_rcpf(x)
#else
#define RCPF(x) (1.0f / (x))
#endif

// ---------------- Kernel A: xp = x @ W_ih^T + b_ih + b_hh  (f16 out to ws) ---
// (unchanged from rounds 5/6, ~130us; not the current bottleneck)
__global__ __launch_bounds__(256) void xproj_kernel(
    const float* __restrict__ x, const float* __restrict__ W_ih,
    const float* __restrict__ b_ih, const float* __restrict__ b_hh,
    _Float16* __restrict__ xp)
{
    const int lane  = threadIdx.x & 63;
    const int wave  = threadIdx.x >> 6;
    const int idx16 = lane & 15;
    const int kq    = lane >> 4;                       // 0..3
    const int r0    = blockIdx.x * 256 + wave * 64;    // wave's 64 m-rows

    half8_t afr[4][4];
    #pragma unroll
    for (int mt = 0; mt < 4; ++mt) {
        #pragma unroll
        for (int sl = 0; sl < 4; ++sl) {
            const float4* ap = (const float4*)(x + (size_t)(r0 + mt * 16 + idx16) * IN_D + sl * 32 + kq * 8);
            float4 a0 = ap[0], a1 = ap[1];
            afr[mt][sl] = half8_t{(_Float16)a0.x, (_Float16)a0.y, (_Float16)a0.z, (_Float16)a0.w,
                                  (_Float16)a1.x, (_Float16)a1.y, (_Float16)a1.z, (_Float16)a1.w};
        }
    }

    for (int nc = 0; nc < 16; ++nc) {
        const int n0 = nc * 16;
        const float bias = b_ih[n0 + idx16] + b_hh[n0 + idx16];

        half8_t bfr[4];
        #pragma unroll
        for (int sl = 0; sl < 4; ++sl) {
            const float4* bp = (const float4*)(W_ih + (size_t)(n0 + idx16) * IN_D + sl * 32 + kq * 8);
            float4 b0 = bp[0], b1 = bp[1];
            bfr[sl] = half8_t{(_Float16)b0.x, (_Float16)b0.y, (_Float16)b0.z, (_Float16)b0.w,
                              (_Float16)b1.x, (_Float16)b1.y, (_Float16)b1.z, (_Float16)b1.w};
        }

        #pragma unroll
        for (int mt = 0; mt < 4; ++mt) {
            f32x4 acc = {0.f, 0.f, 0.f, 0.f};
            #pragma unroll
            for (int sl = 0; sl < 4; ++sl)
                acc = __builtin_amdgcn_mfma_f32_16x16x32_f16(afr[mt][sl], bfr[sl], acc, 0, 0, 0);
            #pragma unroll
            for (int r = 0; r < 4; ++r) {
                const int m = r0 + mt * 16 + kq * 4 + r;
                xp[(size_t)m * HID + n0 + idx16] = (_Float16)(acc[r] + bias);
            }
        }
    }
}

// ---------------- Kernel B: MFMA recurrence + final FC ----------------------
// 4 blocks x 512 threads (8 waves = 2 waves/SIMD for latency hiding — the
// round-6 failure was 1 wave/SIMD exposing every latency; floor is the matrix
// pipe: 128 MFMA/block/step x 4.85cyc = 621 cyc/step).
// Block owns batches [16*bid,+16). Wave owns hidden cols [32*wave,+32):
// 16 MFMA (2 chains of 8) per step. W_hh B-frags = 64 VGPR/lane, resident
// (waves_per_eu(2,2) -> 256-VGPR budget, no allocator pressure).
// h double-buffered in LDS [2][16][HPAD] f16; ONE barrier per step.
// A-frag (lane): batch=c16, k=32s+8g+e (b128 from h row).
// C/D: col(n within tile)=c16, row(batch)=4g+r.  C init = xp value (fused add).
template <int CUR>
static __device__ __forceinline__ void rnn_step(
    _Float16 (*hl)[16][HPAD],
    const half8_t (&B)[2][8],
    _Float16 (&pc)[8],                      // xp for this step: [2*r+nt]
    const _Float16* __restrict__ xb, int t,
    int c16, int g, int wave)
{
    half8_t A[8];
    #pragma unroll
    for (int s = 0; s < 8; ++s)
        A[s] = *(const half8_t*)&hl[CUR][c16][32 * s + 8 * g];

    f32x4 C0, C1;
    #pragma unroll
    for (int r = 0; r < 4; ++r) {
        C0[r] = (float)pc[2 * r];
        C1[r] = (float)pc[2 * r + 1];
    }
    #pragma unroll
    for (int s = 0; s < 8; ++s) {
        C0 = __builtin_amdgcn_mfma_f32_16x16x32_f16(A[s], B[0][s], C0, 0, 0, 0);
        C1 = __builtin_amdgcn_mfma_f32_16x16x32_f16(A[s], B[1][s], C1, 0, 0, 0);
    }

    // tanh + write h(t+1) into the other buffer
    #pragma unroll
    for (int nt = 0; nt < 2; ++nt) {
        f32x4 Cv = nt ? C1 : C0;
        #pragma unroll
        for (int r = 0; r < 4; ++r) {
            // tanh(z) = 1 - 2/(exp2(2*log2e*z)+1); saturates correctly
            const float e = EXP2F(Cv[r] * 2.8853900817779268f);
            const float th = 1.f - 2.f * RCPF(e + 1.f);
            hl[CUR ^ 1][4 * g + r][32 * wave + 16 * nt + c16] = (_Float16)th;
        }
    }

    // prefetch xp for t+2 (consumed above; ~2-step = ~1500cyc hiding window)
    if (t + 2 < S_LEN) {
        #pragma unroll
        for (int r = 0; r < 4; ++r)
            #pragma unroll
            for (int nt = 0; nt < 2; ++nt)
                pc[2 * r + nt] = xb[(size_t)(t + 2) * HID + (size_t)r * S_LEN * HID + 16 * nt];
    }

    __syncthreads();
}

__global__ __launch_bounds__(512)
__attribute__((amdgpu_waves_per_eu(2, 2)))
void rnn_kernel(
    const _Float16* __restrict__ xp, const float* __restrict__ W_hh,
    const float* __restrict__ W_fc, const float* __restrict__ b_fc,
    float* __restrict__ out)
{
    const int tid  = threadIdx.x;
    const int lane = tid & 63;
    const int wave = tid >> 6;          // 0..7: owns n in [32w, 32w+32)
    const int m0   = blockIdx.x * 16;   // batch base
    const int c16  = lane & 15;
    const int g    = lane >> 4;         // 0..3

    __shared__ __align__(16) _Float16 hlds[2][16][HPAD];   // 16.9 KB

    // ---- B fragments: W_hh rows (n = 32w + 16nt + c16), f32 -> f16 ----
    half8_t B[2][8];
    #pragma unroll
    for (int nt = 0; nt < 2; ++nt) {
        const float* wrow = W_hh + (size_t)(wave * 32 + nt * 16 + c16) * HID + g * 8;
        #pragma unroll
        for (int s = 0; s < 8; ++s) {
            const float4* p = (const float4*)(wrow + 32 * s);
            float4 v0 = p[0], v1 = p[1];
            B[nt][s] = half8_t{(_Float16)v0.x, (_Float16)v0.y, (_Float16)v0.z, (_Float16)v0.w,
                               (_Float16)v1.x, (_Float16)v1.y, (_Float16)v1.z, (_Float16)v1.w};
        }
    }

    // ---- h(0) = 0 (both buffers; 4224 dwords) ----
    for (int i = tid; i < 2 * 16 * HPAD / 2; i += 512)
        ((unsigned int*)hlds)[i] = 0u;

    // ---- xp prefetch: value (r,nt) -> batch m0+4g+r, hid 32w+16nt+c16 ----
    const _Float16* xb = xp + (size_t)(m0 + 4 * g) * S_LEN * HID + wave * 32 + c16;
    _Float16 pA[8], pB[8];
    #pragma unroll
    for (int r = 0; r < 4; ++r) {
        #pragma unroll
        for (int nt = 0; nt < 2; ++nt) {
            pA[2 * r + nt] = xb[(size_t)r * S_LEN * HID + 16 * nt];          // t=0
            pB[2 * r + nt] = xb[(size_t)r * S_LEN * HID + HID + 16 * nt];    // t=1
        }
    }

    __syncthreads();

    // ---- 2048 steps, unrolled x2 for static buffer indexing ----
    for (int t = 0; t < S_LEN; t += 2) {
        rnn_step<0>(hlds, B, pA, xb, t,     c16, g, wave);
        rnn_step<1>(hlds, B, pB, xb, t + 1, c16, g, wave);
    }

    // ---- final FC via MFMA: M=16 batch, N=128 out (16/wave), K=256 ----
    // h_final is in hlds[0] (S_LEN even). Loop ended with barrier.
    const int o = wave * 16 + c16;                 // wave < 8 covers 128 outs
    half8_t Bf[8];
    #pragma unroll
    for (int s = 0; s < 8; ++s) {
        const float4* p = (const float4*)(W_fc + (size_t)o * HID + g * 8 + 32 * s);
        float4 v0 = p[0], v1 = p[1];
        Bf[s] = half8_t{(_Float16)v0.x, (_Float16)v0.y, (_Float16)v0.z, (_Float16)v0.w,
                        (_Float16)v1.x, (_Float16)v1.y, (_Float16)v1.z, (_Float16)v1.w};
    }
    half8_t A[8];
    #pragma unroll
    for (int s = 0; s < 8; ++s)
        A[s] = *(const half8_t*)&hlds[0][c16][32 * s + 8 * g];

    const float bf = b_fc[o];
    f32x4 D = {bf, bf, bf, bf};
    #pragma unroll
    for (int s = 0; s < 8; ++s)
        D = __builtin_amdgcn_mfma_f32_16x16x32_f16(A[s], Bf[s], D, 0, 0, 0);

    #pragma unroll
    for (int r = 0; r < 4; ++r) {
        const int b = m0 + 4 * g + r;
        out[(size_t)b * OUT_D + o] = D[r];
    }
}

extern "C" void kernel_launch(void* const* d_in, const int* in_sizes, int n_in,
                              void* d_out, int out_size, void* d_ws, size_t ws_size,
                              hipStream_t stream) {
    const float* x    = (const float*)d_in[0];
    const float* W_ih = (const float*)d_in[1];
    const float* W_hh = (const float*)d_in[2];
    const float* b_ih = (const float*)d_in[3];
    const float* b_hh = (const float*)d_in[4];
    const float* W_fc = (const float*)d_in[5];
    const float* b_fc = (const float*)d_in[6];
    float* outp = (float*)d_out;

    _Float16* xp_ws = (_Float16*)d_ws;   // needs 2048*64*256*2 = 64 MiB

    dim3 gA(S_LEN * B_SZ / 256, 1, 1);   // 512 blocks x 256 rows
    xproj_kernel<<<gA, 256, 0, stream>>>(x, W_ih, b_ih, b_hh, xp_ws);

    rnn_kernel<<<4, 512, 0, stream>>>(xp_ws, W_hh, W_fc, b_fc, outp);
}

// Round 8
// 1456.734 us; speedup vs baseline: 1.6526x; 1.4109x over previous
//
#include <hip/hip_runtime.h>
#include <hip/hip_bf16.h>
#include <hip/hip_fp16.h>

// RNN: INPUT=128, HIDDEN=256, OUTPUT=128, BATCH=64, SEQ=2048
// ref: xp[b,s,h] = sum_i x[b,s,i]*W_ih[h,i] + b_ih[h] + b_hh[h]
//      h = tanh(xp_t + h @ W_hh^T)   (scan over s)
//      out = h_T @ W_fc^T + b_fc

#define S_LEN 2048
#define B_SZ  64
#define IN_D  128
#define HID   256
#define OUT_D 128

typedef _Float16 half2_t __attribute__((ext_vector_type(2)));
typedef _Float16 half8_t __attribute__((ext_vector_type(8)));
typedef float    f32x4   __attribute__((ext_vector_type(4)));

#if __has_builtin(__builtin_amdgcn_fdot2)
#define FDOT2(a, b, c) __builtin_amdgcn_fdot2((a), (b), (c), false)
#else
#define FDOT2(a, b, c) ((c) + (float)(a).x * (float)(b).x + (float)(a).y * (float)(b).y)
#endif

#if __has_builtin(__builtin_amdgcn_exp2f)
#define EXP2F(x) __builtin_amdgcn_exp2f(x)
#else
#define EXP2F(x) exp2f(x)
#endif

#if __has_builtin(__builtin_amdgcn_rcpf)
#define RCPF(x) __builtin_amdgcn_rcpf(x)
#else
#define RCPF(x) (1.0f / (x))
#endif

// ---------------- Kernel A: xp = x @ W_ih^T + b_ih + b_hh  (f16 out to ws) ---
// (unchanged; ~125us measured by subtraction; not the current bottleneck)
__global__ __launch_bounds__(256) void xproj_kernel(
    const float* __restrict__ x, const float* __restrict__ W_ih,
    const float* __restrict__ b_ih, const float* __restrict__ b_hh,
    _Float16* __restrict__ xp)
{
    const int lane  = threadIdx.x & 63;
    const int wave  = threadIdx.x >> 6;
    const int idx16 = lane & 15;
    const int kq    = lane >> 4;                       // 0..3
    const int r0    = blockIdx.x * 256 + wave * 64;    // wave's 64 m-rows

    half8_t afr[4][4];
    #pragma unroll
    for (int mt = 0; mt < 4; ++mt) {
        #pragma unroll
        for (int sl = 0; sl < 4; ++sl) {
            const float4* ap = (const float4*)(x + (size_t)(r0 + mt * 16 + idx16) * IN_D + sl * 32 + kq * 8);
            float4 a0 = ap[0], a1 = ap[1];
            afr[mt][sl] = half8_t{(_Float16)a0.x, (_Float16)a0.y, (_Float16)a0.z, (_Float16)a0.w,
                                  (_Float16)a1.x, (_Float16)a1.y, (_Float16)a1.z, (_Float16)a1.w};
        }
    }

    for (int nc = 0; nc < 16; ++nc) {
        const int n0 = nc * 16;
        const float bias = b_ih[n0 + idx16] + b_hh[n0 + idx16];

        half8_t bfr[4];
        #pragma unroll
        for (int sl = 0; sl < 4; ++sl) {
            const float4* bp = (const float4*)(W_ih + (size_t)(n0 + idx16) * IN_D + sl * 32 + kq * 8);
            float4 b0 = bp[0], b1 = bp[1];
            bfr[sl] = half8_t{(_Float16)b0.x, (_Float16)b0.y, (_Float16)b0.z, (_Float16)b0.w,
                              (_Float16)b1.x, (_Float16)b1.y, (_Float16)b1.z, (_Float16)b1.w};
        }

        #pragma unroll
        for (int mt = 0; mt < 4; ++mt) {
            f32x4 acc = {0.f, 0.f, 0.f, 0.f};
            #pragma unroll
            for (int sl = 0; sl < 4; ++sl)
                acc = __builtin_amdgcn_mfma_f32_16x16x32_f16(afr[mt][sl], bfr[sl], acc, 0, 0, 0);
            #pragma unroll
            for (int r = 0; r < 4; ++r) {
                const int m = r0 + mt * 16 + kq * 4 + r;
                xp[(size_t)m * HID + n0 + idx16] = (_Float16)(acc[r] + bias);
            }
        }
    }
}

// ---------------- Kernel B: dot2 recurrence, 2-way K-split ------------------
// 64 blocks (one per batch), 512 threads (8 waves = 2/SIMD for latency
// hiding). Thread (kh=tid>>8, j=tid&255) computes the K in [128kh,+128)
// partial of hidden unit j with 64 half2 weight VGPRs (small enough that the
// allocator keeps them resident — the 128-reg full-K version of rounds 1-4
// was always spilled/remat'd; VGPR_Count 96-136 < needed).
// h reads are wave-uniform-address b128 -> LDS broadcast, conflict-free.
// Phase 2: BOTH halves redundantly read the other partial + compute tanh (no
// idle finisher waves — round-5's mistake); only kh=0 writes h. 2 barriers.
__global__ __launch_bounds__(512) void rnn_kernel(
    const _Float16* __restrict__ xp, const float* __restrict__ W_hh,
    const float* __restrict__ W_fc, const float* __restrict__ b_fc,
    float* __restrict__ out)
{
    const int b   = blockIdx.x;
    const int tid = threadIdx.x;
    const int j   = tid & 255;
    const int kh  = tid >> 8;                 // 0..1 (wave-uniform)

    __shared__ __align__(16) _Float16 hbuf[2][HID];   // 1 KB
    __shared__ __align__(16) float    part[2][HID];   // 2 KB

    // weights: W_hh[j][128*kh .. +128) -> 64 half2 VGPRs
    half2_t w[64];
    {
        const float4* wr = (const float4*)(W_hh + (size_t)j * HID + 128 * kh);
        #pragma unroll
        for (int c = 0; c < 32; ++c) {
            float4 v = wr[c];
            w[2 * c]     = half2_t{(_Float16)v.x, (_Float16)v.y};
            w[2 * c + 1] = half2_t{(_Float16)v.z, (_Float16)v.w};
        }
    }

    if (tid < HID) hbuf[0][tid] = (_Float16)0.f;

    // xp stream [b][s][h]; both halves load redundantly (L2/L3 absorbs)
    const _Float16* xpb = xp + (size_t)b * S_LEN * HID + j;
    float p0 = (float)xpb[0];
    float p1 = (float)xpb[HID];

    __syncthreads();

    for (int t = 0; t < S_LEN; ++t) {
        const int rb = t & 1;
        // phase 1: partial dot over this thread's K half.
        // hp is wave-uniform -> broadcast ds_read_b128, no bank conflicts.
        const float4* hp = (const float4*)&hbuf[rb][128 * kh];
        float a0 = 0.f, a1 = 0.f, a2 = 0.f, a3 = 0.f;
        #pragma unroll
        for (int c = 0; c < 16; ++c) {
            float4 hv = hp[c];
            union { float f; half2_t h; } u0, u1, u2, u3;
            u0.f = hv.x; u1.f = hv.y; u2.f = hv.z; u3.f = hv.w;
            a0 = FDOT2(w[4 * c + 0], u0.h, a0);
            a1 = FDOT2(w[4 * c + 1], u1.h, a1);
            a2 = FDOT2(w[4 * c + 2], u2.h, a2);
            a3 = FDOT2(w[4 * c + 3], u3.h, a3);
        }
        const float own = (a0 + a1) + (a2 + a3);
        part[kh][j] = own;
        __syncthreads();

        // phase 2: combine halves (redundant on both), tanh, kh=0 writes h
        const float z = part[kh ^ 1][j] + own + p0;
        p0 = p1;
        const int tn = (t + 2 < S_LEN) ? (t + 2) : (S_LEN - 1);
        p1 = (float)xpb[(size_t)tn * HID];
        // tanh(z) = 1 - 2/(exp2(2*log2e*z)+1); saturates correctly at +-inf
        const float e = EXP2F(z * 2.8853900817779268f);
        const float th = 1.f - 2.f * RCPF(e + 1.f);
        if (kh == 0) hbuf[rb ^ 1][j] = (_Float16)th;
        __syncthreads();
    }

    // final FC: out[b][o] = sum_j h[j]*W_fc[o][j] + b_fc[o]
    // final h is in hbuf[0] (t=2047: rb=1 -> wrote hbuf[0]); loop ends with barrier
    if (tid < OUT_D) {
        float acc2 = b_fc[tid];
        const float4* wp = (const float4*)(W_fc + (size_t)tid * HID);
        const _Float16* hf = hbuf[0];
        #pragma unroll 8
        for (int c = 0; c < 64; ++c) {
            float4 wv = wp[c];
            acc2 += wv.x * (float)hf[4 * c + 0] + wv.y * (float)hf[4 * c + 1] +
                    wv.z * (float)hf[4 * c + 2] + wv.w * (float)hf[4 * c + 3];
        }
        out[(size_t)b * OUT_D + tid] = acc2;
    }
}

extern "C" void kernel_launch(void* const* d_in, const int* in_sizes, int n_in,
                              void* d_out, int out_size, void* d_ws, size_t ws_size,
                              hipStream_t stream) {
    const float* x    = (const float*)d_in[0];
    const float* W_ih = (const float*)d_in[1];
    const float* W_hh = (const float*)d_in[2];
    const float* b_ih = (const float*)d_in[3];
    const float* b_hh = (const float*)d_in[4];
    const float* W_fc = (const float*)d_in[5];
    const float* b_fc = (const float*)d_in[6];
    float* outp = (float*)d_out;

    _Float16* xp_ws = (_Float16*)d_ws;   // needs 2048*64*256*2 = 64 MiB

    dim3 gA(S_LEN * B_SZ / 256, 1, 1);   // 512 blocks x 256 rows
    xproj_kernel<<<gA, 256, 0, stream>>>(x, W_ih, b_ih, b_hh, xp_ws);

    rnn_kernel<<<B_SZ, 512, 0, stream>>>(xp_ws, W_hh, W_fc, b_fc, outp);
}